// Round 2
// baseline (155.246 us; speedup 1.0000x reference)
//
#include <hip/hip_runtime.h>
#include <hip/hip_bf16.h>

// out[b,0,f,t] = sum_{k=0}^{768} kernels[f,k] * x[b,0,t-k]  (zero-padded left).
// FFT reference has no circular wrap (16384 >= 8192+769-1), so direct conv is exact.
//
// MFMA Toeplitz-GEMM: M=f (pad 32), N=t, K=k (pad [-8,792)).
// v_mfma_f32_32x32x16_bf16; diagonal register-reuse of Toeplitz B-fragments:
//   frag(kblk i+1, ttile wt+1) == frag(i, wt)  -> 4-deep ring, 1 new pair/iter.
// Alignment: 8 shifted bf16 copies of x in LDS (per-lane copy = s&7);
// h stored k-reversed so both A and B fragment reads are straight aligned b128.

#define BATCH 128
#define SEQ   8192
#define NF    20
#define KLEN  769

#define THREADS 512
#define CHUNK   2048
#define NCHUNK  (SEQ / CHUNK)   // 4
#define KT      25              // k32-blocks covering k in [-8, 792)

#define HSTRIDE_B 1616          // 808 bf16 elems/row (16B-mult, !=0 mod 128)
#define XSTRIDE_B 5776          // bytes/copy: 16B-mult, == 16 mod 128 (bank spread)
#define XN        2864          // elems per x copy
#define XBYTES    (8 * XSTRIDE_B)   // 46208
#define HBYTES    (32 * HSTRIDE_B)  // 51712
#define LDSB      (XBYTES + HBYTES) // 97920

typedef short bf16x8 __attribute__((ext_vector_type(8)));
typedef float f32x16 __attribute__((ext_vector_type(16)));

static __device__ __forceinline__ unsigned short f2bf(float v) {
    __hip_bfloat16 h = __float2bfloat16(v);
    return *reinterpret_cast<unsigned short*>(&h);
}

__global__ __launch_bounds__(THREADS, 2)
void bpf_mfma(const float* __restrict__ xg, const float* __restrict__ kg,
              float* __restrict__ out) {
    extern __shared__ char smem[];
    char* xs = smem;            // 8 shifted x copies, bf16
    char* hs = smem + XBYTES;   // h, k-reversed + zero-padded, bf16

    const int tid = threadIdx.x;
    const int bid = blockIdx.x;
    const int b   = bid >> 2;
    const int T0  = (bid & 3) * CHUNK;
    const int E0  = T0 - 800;

    // ---- stage h: hs[f][p] = h[f][791-p], zero outside [0,769) or f>=20 ----
    for (int idx = tid; idx < 32 * 800; idx += THREADS) {
        int f = idx / 800;
        int p = idx - f * 800;
        int k = 791 - p;
        float v = 0.0f;
        if (f < NF && k >= 0 && k < KLEN) v = kg[f * KLEN + k];
        *reinterpret_cast<unsigned short*>(hs + f * HSTRIDE_B + 2 * p) = f2bf(v);
    }
    // ---- stage x copies: copy rho elem e = x[E0 + rho + e] (zero-guarded) ----
    const float* xb = xg + (size_t)b * SEQ;
    for (int rho = 0; rho < 8; ++rho) {
        char* xr = xs + rho * XSTRIDE_B;
        for (int e = tid; e < XN; e += THREADS) {
            int g = E0 + rho + e;
            float v = (g >= 0 && g < SEQ) ? xb[g] : 0.0f;
            *reinterpret_cast<unsigned short*>(xr + 2 * e) = f2bf(v);
        }
    }
    __syncthreads();

    const int lane = tid & 63;
    const int wid  = tid >> 6;
    const int c    = lane & 31;   // A row (=f), B col (=t-offset), D col
    const int g2   = lane >> 5;

    // A (h) base: row c, k-reversed; offsets sub-a: 1584-64i, sub-b: 1552-64i
    const char* Abase = hs + c * HSTRIDE_B - 16 * g2;

    float* outb = out + (size_t)b * NF * SEQ;

    for (int ti = 0; ti < 2; ++ti) {
        const int n0     = T0 + (wid + 8 * ti) * 128;   // task: 128 t-cols
        const int s_base = n0 + c + 1 - 8 * g2 - 784;   // min window start (i=24,sub-b)
        const int rho    = s_base & 7;                  // per-lane shifted-copy select
        const int ebase  = s_base - rho - E0;           // >=0, == 0 mod 8
        const char* Bbase = xs + rho * XSTRIDE_B + 2 * ebase;

        f32x16 acc[4];
#pragma unroll
        for (int wt = 0; wt < 4; ++wt)
#pragma unroll
            for (int r = 0; r < 16; ++r) acc[wt][r] = 0.0f;

        // prologue: pair(0,wt) -> ring[(4-wt)&3]; byte off sub-a 1568+64wt, sub-b 1536+64wt
        bf16x8 ring[4][2];
#pragma unroll
        for (int wt = 0; wt < 4; ++wt) {
            ring[(4 - wt) & 3][0] = *reinterpret_cast<const bf16x8*>(Bbase + 1568 + 64 * wt);
            ring[(4 - wt) & 3][1] = *reinterpret_cast<const bf16x8*>(Bbase + 1536 + 64 * wt);
        }

#pragma unroll
        for (int i = 0; i < KT; ++i) {
            bf16x8 na, nb;
            if (i < KT - 1) {   // prefetch pair(i+1, 0): offsets 64*(23-i)+32 / 64*(23-i)
                na = *reinterpret_cast<const bf16x8*>(Bbase + 64 * (23 - i) + 32);
                nb = *reinterpret_cast<const bf16x8*>(Bbase + 64 * (23 - i));
            }
            bf16x8 a0 = *reinterpret_cast<const bf16x8*>(Abase + 1584 - 64 * i);
            bf16x8 a1 = *reinterpret_cast<const bf16x8*>(Abase + 1552 - 64 * i);
#pragma unroll
            for (int wt = 0; wt < 4; ++wt) {
                acc[wt] = __builtin_amdgcn_mfma_f32_32x32x16_bf16(
                    a0, ring[(i - wt) & 3][0], acc[wt], 0, 0, 0);
                acc[wt] = __builtin_amdgcn_mfma_f32_32x32x16_bf16(
                    a1, ring[(i - wt) & 3][1], acc[wt], 0, 0, 0);
            }
            if (i < KT - 1) {
                ring[(i + 1) & 3][0] = na;
                ring[(i + 1) & 3][1] = nb;
            }
        }

        // D: col = lane&31 (t), row f = (r&3) + 8*(r>>2) + 4*g2  [m74/m101]
#pragma unroll
        for (int wt = 0; wt < 4; ++wt) {
            const int tcol = n0 + 32 * wt + c;
#pragma unroll
            for (int r = 0; r < 16; ++r) {
                const int f = (r & 3) + 8 * (r >> 2) + 4 * g2;
                if (f < NF) outb[f * SEQ + tcol] = acc[wt][r];
            }
        }
    }
}

extern "C" void kernel_launch(void* const* d_in, const int* in_sizes, int n_in,
                              void* d_out, int out_size, void* d_ws, size_t ws_size,
                              hipStream_t stream) {
    const float* x    = (const float*)d_in[0];   // (128,1,8192) f32
    const float* kern = (const float*)d_in[1];   // (20,769)     f32
    float* out = (float*)d_out;                  // (128,1,20,8192) f32

    (void)d_ws; (void)ws_size; (void)in_sizes; (void)n_in; (void)out_size;

    hipFuncSetAttribute(reinterpret_cast<const void*>(bpf_mfma),
                        hipFuncAttributeMaxDynamicSharedMemorySize, LDSB);
    bpf_mfma<<<BATCH * NCHUNK, THREADS, LDSB, stream>>>(x, kern, out);
}